// Round 10
// baseline (143.328 us; speedup 1.0000x reference)
//
#include <hip/hip_runtime.h>
#include <cstdint>
#include <cstddef>

#define B_   16
#define N_   2048
#define DN   64
#define DQ   256     // 4*D_NET
#define HID_ 128
#define SEQ_ 18
#define OUTR 2066
#define KVB  32

typedef __attribute__((ext_vector_type(4)))  float f32x4;
typedef __attribute__((ext_vector_type(16))) float f32x16;
typedef __attribute__((ext_vector_type(8)))  short bf16x8;

__device__ __forceinline__ unsigned cvtpk(float lo, float hi) {
  unsigned w;
  asm("v_cvt_pk_bf16_f32 %0, %1, %2" : "=v"(w) : "v"(lo), "v"(hi));
  return w;
}
__device__ __forceinline__ short f2bf(float f) {
  union { float f; unsigned u; } v; v.f = f;
  unsigned r = v.u + 0x7fffu + ((v.u >> 16) & 1u);
  return (short)(r >> 16);
}
__device__ __forceinline__ bf16x8 cvt8(const float* p) {
  f32x4 a = *(const f32x4*)p, b = *(const f32x4*)(p + 4);
  union { unsigned u[4]; bf16x8 v; } r;
  r.u[0] = cvtpk(a[0], a[1]); r.u[1] = cvtpk(a[2], a[3]);
  r.u[2] = cvtpk(b[0], b[1]); r.u[3] = cvtpk(b[2], b[3]);
  return r.v;
}
__device__ __forceinline__ float hadd4(f32x4 v) { return (v[0] + v[1]) + (v[2] + v[3]); }

// redistribute 32x32 C-layout rows into MFMA-fragment k-order (A or B frag)
__device__ __forceinline__ bf16x8 mkfrag(unsigned wa, unsigned wb,
                                         unsigned wc, unsigned wd, bool hi) {
  unsigned sa = (unsigned)__shfl_xor((int)wa, 32);
  unsigned sb = (unsigned)__shfl_xor((int)wb, 32);
  unsigned sc = (unsigned)__shfl_xor((int)wc, 32);
  unsigned sd = (unsigned)__shfl_xor((int)wd, 32);
  union { unsigned u[4]; bf16x8 v; } r;
  r.u[0] = hi ? sc : wa;
  r.u[1] = hi ? sd : wb;
  r.u[2] = hi ? wc : sa;
  r.u[3] = hi ? wd : sb;
  return r.v;
}

// ======================= proj kernel (r8-verified): Q, K, G = netW·V^T frags ====
__global__ __launch_bounds__(512) void proj_kernel(
    const float* __restrict__ net, const float* __restrict__ Wq, const float* __restrict__ bq,
    const float* __restrict__ Wk, const float* __restrict__ bk,
    const float* __restrict__ Wv, const float* __restrict__ bv,
    const float* __restrict__ netW,
    short* __restrict__ Qb, short* __restrict__ Kb, short* __restrict__ Gf) {
  __shared__ char psm[98304];          // wl 32KB (one matrix at a time) | Vrm 64KB
  short* wl = (short*)psm;
  char* vrm = psm + 32768;

  const int gid = blockIdx.x;
  const int b = gid >> 4;
  const int r0 = (gid & 15) * 128;
  const int t = threadIdx.x;
  const int w = t >> 6, lane = t & 63, ln = lane & 15, g = lane >> 4;
  const int rw = r0 + w * 16;
  const int xk = (ln & 7) << 4;

  bf16x8 af[2];
#pragma unroll
  for (int c = 0; c < 2; ++c)
    af[c] = cvt8(net + ((size_t)b * N_ + rw + ln) * DN + c * 32 + g * 8);

  const float* Ws[3] = {Wq, Wk, Wv};
  for (int m = 0; m < 3; ++m) {
    __syncthreads();
#pragma unroll
    for (int it = 0; it < 8; ++it) {         // stage W[m] 256x64 f32 -> bf16 swizzled (32KB)
      int idx = it * 512 + t;
      int row = idx >> 4, c8 = idx & 15;
      f32x4 v = *(const f32x4*)(Ws[m] + row * 64 + c8 * 4);
      int byo = row * 128 + ((c8 * 8) ^ ((row & 7) << 4));
      *(uint2*)((char*)wl + byo) = make_uint2(cvtpk(v[0], v[1]), cvtpk(v[2], v[3]));
    }
    __syncthreads();
    if (m < 2) {
      const float* bias = (m == 0) ? bq : bk;
      short* dst = (m == 0) ? Qb : Kb;
      const float sc = (m == 0) ? 0.125f : 1.0f;   // fold 1/sqrt(64) into Q
#pragma unroll
      for (int tt = 0; tt < 16; ++tt) {
        f32x4 acc = {0.f, 0.f, 0.f, 0.f};
#pragma unroll
        for (int c = 0; c < 2; ++c) {
          int byo = (tt * 16 + ln) * 128 + ((c * 64 + g * 16) ^ xk);
          bf16x8 wf = *(const bf16x8*)((char*)wl + byo);
          acc = __builtin_amdgcn_mfma_f32_16x16x32_bf16(wf, af[c], acc, 0, 0, 0);
        }
        f32x4 b4 = *(const f32x4*)(bias + tt * 16 + g * 4);
        uint2 u = make_uint2(cvtpk((acc[0] + b4[0]) * sc, (acc[1] + b4[1]) * sc),
                             cvtpk((acc[2] + b4[2]) * sc, (acc[3] + b4[3]) * sc));
        *(uint2*)(dst + ((size_t)b * N_ + rw + ln) * DQ + tt * 16 + g * 4) = u;
      }
    } else {
      // V tile -> bf16 row-major in LDS (Vrm[nn][d], 512B rows, XOR swizzle)
#pragma unroll
      for (int tt = 0; tt < 16; ++tt) {
        f32x4 acc = {0.f, 0.f, 0.f, 0.f};
#pragma unroll
        for (int c = 0; c < 2; ++c) {
          int byo = (tt * 16 + ln) * 128 + ((c * 64 + g * 16) ^ xk);
          bf16x8 wf = *(const bf16x8*)((char*)wl + byo);
          acc = __builtin_amdgcn_mfma_f32_16x16x32_bf16(af[c], wf, acc, 0, 0, 0);
        }
        float bias = bv[tt * 16 + ln];
        int d = tt * 16 + ln;
#pragma unroll
        for (int r = 0; r < 4; ++r) {
          int nn = w * 16 + g * 4 + r;
          int byte = nn * 512 + ((d * 2) ^ ((nn & 7) << 4));
          *(short*)(vrm + byte) = f2bf(acc[r] + bias);
        }
      }
    }
  }
  __syncthreads();

  // ---- G phase: G^T tiles C[n][d'] = V[n][:]·netW[d'][:]; mkfrag -> PV A-frags ----
  const int l31 = lane & 31, h = lane >> 5;
  const bool hb = (h != 0);
#pragma unroll
  for (int j = 0; j < 2; ++j) {
    int ti = w * 2 + j;
    int nt = ti >> 2, dt = ti & 3;
    f32x16 C;
#pragma unroll
    for (int r = 0; r < 16; ++r) C[r] = 0.f;
    int n = nt * 32 + l31;
#pragma unroll
    for (int dc = 0; dc < 16; ++dc) {
      bf16x8 A = *(const bf16x8*)(vrm + n * 512 + ((dc * 32 + h * 16) ^ ((n & 7) << 4)));
      bf16x8 Bf = cvt8(netW + (size_t)(dt * 32 + l31) * DQ + dc * 16 + h * 8);
      C = __builtin_amdgcn_mfma_f32_32x32x16_bf16(A, Bf, C, 0, 0, 0);
    }
    unsigned a0 = cvtpk(C[0],  C[1]),  a1 = cvtpk(C[2],  C[3]);
    unsigned a2 = cvtpk(C[4],  C[5]),  a3 = cvtpk(C[6],  C[7]);
    unsigned a4 = cvtpk(C[8],  C[9]),  a5 = cvtpk(C[10], C[11]);
    unsigned a6 = cvtpk(C[12], C[13]), a7 = cvtpk(C[14], C[15]);
    bf16x8 f0 = mkfrag(a0, a1, a2, a3, hb);   // k = n 0..15
    bf16x8 f1 = mkfrag(a4, a5, a6, a7, hb);   // k = n 16..31
    size_t base = (((size_t)b * 64 + (r0 >> 5) + nt) * 8 + dt * 2) * 512;
    *(bf16x8*)(Gf + base + lane * 8)       = f0;
    *(bf16x8*)(Gf + base + 512 + lane * 8) = f1;
  }
}

// ======================= sfc (512 threads, MFMA qkv/outproj) =======================
struct SfcS {
  float xs[SEQ_][132];
  float qkv[SEQ_][388];
  float scs[4][SEQ_][19];
  float sinb[SEQ_][32];
  float ffh[SEQ_][8];
  float maskv[SEQ_];
  short xbf[32 * 128];     // bf16 mirror [32][128], XOR-swizzled, rows 18..31 zero
};

__device__ __forceinline__ void par_ln(SfcS& S, const float* __restrict__ lw,
                                       const float* __restrict__ lb, int w, int lane) {
  float w0 = lw[lane * 2], w1 = lw[lane * 2 + 1];
  float b0 = lb[lane * 2], b1 = lb[lane * 2 + 1];
  for (int r = w; r < SEQ_; r += 8) {
    float2 v = *(const float2*)&S.qkv[r][128 + lane * 2];
    float s1 = v.x + v.y;
    float s2 = v.x * v.x + v.y * v.y;
#pragma unroll
    for (int off = 1; off < 64; off <<= 1) {
      s1 += __shfl_xor(s1, off);
      s2 += __shfl_xor(s2, off);
    }
    float mu = s1 * 0.0078125f;
    float var = s2 * 0.0078125f - mu * mu;
    float rsd = rsqrtf(var + 1e-5f);
    S.xs[r][lane * 2]     = (v.x - mu) * rsd * w0 + b0;
    S.xs[r][lane * 2 + 1] = (v.y - mu) * rsd * w1 + b1;
  }
}

// copy rows[0..17] of f32 matrix (stride) into swizzled bf16 [32][128] tile
__device__ __forceinline__ void rows_to_bf(const float* __restrict__ src, int stride,
                                           char* __restrict__ xbf, int t) {
  for (int i = t; i < SEQ_ * 16; i += 512) {
    int row = i >> 4, c8 = i & 15;
    const float* p = src + row * stride + c8 * 8;
    f32x4 a = *(const f32x4*)p;
    f32x4 b = *(const f32x4*)(p + 4);
    uint4 u;
    u.x = cvtpk(a[0], a[1]); u.y = cvtpk(a[2], a[3]);
    u.z = cvtpk(b[0], b[1]); u.w = cvtpk(b[2], b[3]);
    int byo = row * 256 + ((c8 * 16) ^ ((row & 7) << 4));
    *(uint4*)(xbf + byo) = u;
  }
}

__device__ void sfc_body(
    int b, SfcS& S,
    const float* __restrict__ sfc_state, const int* __restrict__ node_pair,
    const float* __restrict__ node_embed, const float* __restrict__ sfcW,
    const float* __restrict__ sfcb, const float* __restrict__ pos,
    const float* __restrict__ qkvW, const float* __restrict__ qkvB,
    const float* __restrict__ outW, const float* __restrict__ outB,
    const float* __restrict__ ln1w, const float* __restrict__ ln1b,
    const float* __restrict__ l1w, const float* __restrict__ l1b,
    const float* __restrict__ l2w, const float* __restrict__ l2b,
    const float* __restrict__ ln2w, const float* __restrict__ ln2b,
    float* __restrict__ out) {
  const int t = threadIdx.x;            // 0..511
  const int w = t >> 6, lane = t & 63, ln = lane & 15, g = lane >> 4;
  char* xbf = (char*)S.xbf;
  const int xk2 = (ln & 7) << 4;

  ((uint4*)xbf)[t] = make_uint4(0, 0, 0, 0);  // 512 x 16B = full tile; rows 18..31 stay zero

  for (int i = t; i < SEQ_ * 32; i += 512) {
    int s = i >> 5, d = i & 31;
    float v;
    if (s == 0)       v = node_embed[node_pair[b * 2 + 0] * 32 + d];
    else if (s == 17) v = node_embed[node_pair[b * 2 + 1] * 32 + d];
    else              v = sfc_state[((size_t)b * 16 + (s - 1)) * 32 + d];
    S.sinb[s][d] = v;
  }
  __syncthreads();
  if (t < SEQ_) {
    float sum = 0.f;
#pragma unroll
    for (int d = 0; d < 32; ++d) sum += fabsf(S.sinb[t][d]);
    S.maskv[t] = (sum == 0.f) ? -1e9f : 0.f;
  }
  {
    int hh = t & 127, part = t >> 7;    // 4 parts
    f32x4 wr[8];
#pragma unroll
    for (int j = 0; j < 8; ++j) wr[j] = *(const f32x4*)(sfcW + hh * 32 + j * 4);
    for (int si = part; si < SEQ_; si += 4) {
      f32x4 a = {0.f, 0.f, 0.f, 0.f};
#pragma unroll
      for (int j = 0; j < 8; ++j) a += wr[j] * (*(const f32x4*)&S.sinb[si][j * 4]);
      S.xs[si][hh] = hadd4(a) + sfcb[hh] + pos[si * HID_ + hh];
    }
  }
  __syncthreads();

  for (int ll = 0; ll < 2; ++ll) {
    rows_to_bf(&S.xs[0][0], 132, xbf, t);
    __syncthreads();
    // --- qkv = x @ W^T + b : MFMA (waves 0..3) ---
    if (t < 256) {
      bf16x8 af[2][4];
#pragma unroll
      for (int m = 0; m < 2; ++m)
#pragma unroll
        for (int k = 0; k < 4; ++k)
          af[m][k] = *(const bf16x8*)(xbf + (m * 16 + ln) * 256 + ((k * 64 + g * 16) ^ xk2));
#pragma unroll
      for (int i = 0; i < 6; ++i) {
        int nt = w + i * 4;
        const float* wp = qkvW + ((size_t)ll * 384 + nt * 16 + ln) * HID_;
        f32x4 a0 = {0.f, 0.f, 0.f, 0.f}, a1 = {0.f, 0.f, 0.f, 0.f};
#pragma unroll
        for (int k = 0; k < 4; ++k) {
          bf16x8 wf = cvt8(wp + k * 32 + g * 8);
          a0 = __builtin_amdgcn_mfma_f32_16x16x32_bf16(wf, af[0][k], a0, 0, 0, 0);
          a1 = __builtin_amdgcn_mfma_f32_16x16x32_bf16(wf, af[1][k], a1, 0, 0, 0);
        }
        f32x4 b4 = *(const f32x4*)(qkvB + ll * 384 + nt * 16 + g * 4);
#pragma unroll
        for (int r = 0; r < 4; ++r) {
          S.qkv[ln][nt * 16 + g * 4 + r] = a0[r] + b4[r];
          if (ln < 2) S.qkv[16 + ln][nt * 16 + g * 4 + r] = a1[r] + b4[r];
        }
      }
    }
    __syncthreads();
    for (int i = t; i < 4 * SEQ_ * SEQ_; i += 512) {
      int hh = i / (SEQ_ * SEQ_), rem = i - hh * SEQ_ * SEQ_;
      int qi = rem / SEQ_, kj = rem - qi * SEQ_;
      f32x4 a = {0.f, 0.f, 0.f, 0.f};
#pragma unroll
      for (int j = 0; j < 8; ++j)
        a += (*(const f32x4*)&S.qkv[qi][hh * 32 + j * 4]) *
             (*(const f32x4*)&S.qkv[kj][128 + hh * 32 + j * 4]);
      S.scs[hh][qi][kj] = hadd4(a) * 0.17677669529663687f + S.maskv[kj];
    }
    __syncthreads();
    if (t < 4 * SEQ_) {
      int hh = t / SEQ_, qi = t - hh * SEQ_;
      float mx = -1e30f;
#pragma unroll
      for (int j = 0; j < SEQ_; ++j) mx = fmaxf(mx, S.scs[hh][qi][j]);
      float sum = 0.f;
#pragma unroll
      for (int j = 0; j < SEQ_; ++j) {
        float e = __expf(S.scs[hh][qi][j] - mx);
        S.scs[hh][qi][j] = e; sum += e;
      }
      float inv = 1.f / sum;
#pragma unroll
      for (int j = 0; j < SEQ_; ++j) S.scs[hh][qi][j] *= inv;
    }
    __syncthreads();
    for (int i = t; i < SEQ_ * HID_; i += 512) {
      int s = i >> 7, hd = i & 127, hh = hd >> 5;
      float a = 0.f;
#pragma unroll
      for (int j = 0; j < SEQ_; ++j) a += S.scs[hh][s][j] * S.qkv[j][256 + hd];
      S.qkv[s][hd] = a;
    }
    __syncthreads();
    rows_to_bf(&S.qkv[0][0], 388, xbf, t);
    __syncthreads();
    // --- out-proj + residual : MFMA (waves 0..3) ---
    if (t < 256) {
      bf16x8 af[2][4];
#pragma unroll
      for (int m = 0; m < 2; ++m)
#pragma unroll
        for (int k = 0; k < 4; ++k)
          af[m][k] = *(const bf16x8*)(xbf + (m * 16 + ln) * 256 + ((k * 64 + g * 16) ^ xk2));
#pragma unroll
      for (int i = 0; i < 2; ++i) {
        int nt = w + i * 4;
        const float* wp = outW + ((size_t)ll * HID_ + nt * 16 + ln) * HID_;
        f32x4 a0 = {0.f, 0.f, 0.f, 0.f}, a1 = {0.f, 0.f, 0.f, 0.f};
#pragma unroll
        for (int k = 0; k < 4; ++k) {
          bf16x8 wf = cvt8(wp + k * 32 + g * 8);
          a0 = __builtin_amdgcn_mfma_f32_16x16x32_bf16(wf, af[0][k], a0, 0, 0, 0);
          a1 = __builtin_amdgcn_mfma_f32_16x16x32_bf16(wf, af[1][k], a1, 0, 0, 0);
        }
        f32x4 b4 = *(const f32x4*)(outB + ll * HID_ + nt * 16 + g * 4);
#pragma unroll
        for (int r = 0; r < 4; ++r) {
          int h = nt * 16 + g * 4 + r;
          S.qkv[ln][128 + h] = S.xs[ln][h] + a0[r] + b4[r];
          if (ln < 2) S.qkv[16 + ln][128 + h] = S.xs[16 + ln][h] + a1[r] + b4[r];
        }
      }
    }
    __syncthreads();
    par_ln(S, ln1w + ll * HID_, ln1b + ll * HID_, w, lane);
    __syncthreads();
    if (t < SEQ_ * 8) {
      int s = t >> 3, oo = t & 7;
      const float* wp = l1w + ((size_t)ll * 8 + oo) * HID_;
      f32x4 a = {0.f, 0.f, 0.f, 0.f};
#pragma unroll
      for (int j = 0; j < 32; ++j)
        a += (*(const f32x4*)(wp + j * 4)) * (*(const f32x4*)&S.xs[s][j * 4]);
      S.ffh[s][oo] = fmaxf(hadd4(a) + l1b[ll * 8 + oo], 0.f);
    }
    __syncthreads();
    for (int i = t; i < SEQ_ * HID_; i += 512) {
      int s = i >> 7, h2 = i & 127;
      const float* wp = l2w + ((size_t)ll * HID_ + h2) * 8;
      float a = 0.f;
#pragma unroll
      for (int j = 0; j < 8; ++j) a += wp[j] * S.ffh[s][j];
      S.qkv[s][128 + h2] = S.xs[s][h2] + a + l2b[ll * HID_ + h2];
    }
    __syncthreads();
    par_ln(S, ln2w + ll * HID_, ln2b + ll * HID_, w, lane);
    __syncthreads();
  }
  for (int i = t; i < SEQ_ * HID_; i += 512) {
    int s = i >> 7, h2 = i & 127;
    out[((size_t)b * OUTR + 2048 + s) * HID_ + h2] = S.xs[s][h2];
  }
}

union ASmem { alignas(16) char attn[66048]; SfcS sfc; };   // 2x32KB K dbuf + 512B lsums

// ======================= attn: 8 waves, kv-split in block; + sfc blocks 0..15 ====
__global__ __launch_bounds__(512, 2) void attn_sfc_kernel(
    const short* __restrict__ Qb, const short* __restrict__ Kb,
    const short* __restrict__ Gf, const float* __restrict__ netb,
    const float* __restrict__ sfc_state, const int* __restrict__ node_pair,
    const float* __restrict__ node_embed, const float* __restrict__ sfcW,
    const float* __restrict__ sfcb, const float* __restrict__ pos,
    const float* __restrict__ qkvW, const float* __restrict__ qkvB,
    const float* __restrict__ outW, const float* __restrict__ outB,
    const float* __restrict__ ln1w, const float* __restrict__ ln1b,
    const float* __restrict__ l1w, const float* __restrict__ l1b,
    const float* __restrict__ l2w, const float* __restrict__ l2b,
    const float* __restrict__ ln2w, const float* __restrict__ ln2b,
    float* __restrict__ out) {
  __shared__ ASmem sm;
  if (blockIdx.x < 16) {
    sfc_body(blockIdx.x, sm.sfc, sfc_state, node_pair, node_embed, sfcW, sfcb, pos,
             qkvW, qkvB, outW, outB, ln1w, ln1b, l1w, l1b, l2w, l2b, ln2w, ln2b, out);
    return;
  }
  const int i = blockIdx.x - 16;
  const int b = (i & 7) * 2 + ((i >> 3) & 1);   // batch <-> XCD affinity
  const int q0 = (i >> 4) * 128;
  const int t = threadIdx.x;
  const int w = t >> 6, l = t & 63;
  const int gr = w >> 2, wq = w & 3;            // kv-group, q-subtile
  const int l31 = l & 31, h = l >> 5, l7 = l & 7;
  const int qw = q0 + wq * 32;
  const bool hb = (h != 0);

  const short* Kg = Kb + ((size_t)b * N_ + (size_t)gr * 1024) * DQ;
  char* kb0 = sm.attn + gr * 32768;
  char* kb1 = kb0 + 16384;

  bf16x8 qf[16];
  const short* Qrow = Qb + ((size_t)b * N_ + qw + l31) * DQ + h * 8;
#pragma unroll
  for (int kc = 0; kc < 16; ++kc)
    qf[kc] = *(const bf16x8*)(Qrow + kc * 16);

  f32x16 o[4];
#pragma unroll
  for (int dt = 0; dt < 4; ++dt)
#pragma unroll
    for (int r = 0; r < 16; ++r) o[dt][r] = 0.f;
  float lsum = 0.f;

  auto stage_k = [&](int tile, char* dst) {
#pragma unroll
    for (int it = 0; it < 4; ++it) {
      int idx = wq * 4 + it;
      int row = idx * 2 + h;
      int gcol = (l31 * 16) ^ ((row & 7) << 4);
      const char* src = (const char*)(Kg + (size_t)(tile * KVB + row) * DQ) + gcol;
      __builtin_amdgcn_global_load_lds(
          (const __attribute__((address_space(1))) void*)src,
          (__attribute__((address_space(3))) void*)(dst + idx * 1024), 16, 0, 0);
    }
  };

  stage_k(0, kb0);
  __syncthreads();

  const short* Gb = Gf + (size_t)b * 64 * 4096;
  for (int tt = 0; tt < 32; ++tt) {
    char* kc_ = (tt & 1) ? kb1 : kb0;
    if (tt < 31) stage_k(tt + 1, (tt & 1) ? kb0 : kb1);
    // prefetch G frags for this tile (L2)
    const short* gt = Gb + (size_t)(gr * 32 + tt) * 4096 + l * 8;
    bf16x8 vw[8];
#pragma unroll
    for (int f = 0; f < 8; ++f)
      vw[f] = *(const bf16x8*)(gt + f * 512);
    // QK^T (swapped: S^T[32 kv][32 q], q lane-local)
    f32x16 s;
#pragma unroll
    for (int r = 0; r < 16; ++r) s[r] = 0.f;
    __builtin_amdgcn_s_setprio(1);
#pragma unroll
    for (int kc = 0; kc < 16; ++kc) {
      bf16x8 kf = *(const bf16x8*)(kc_ + l31 * 512 + ((kc * 32 + h * 16) ^ (l7 << 4)));
      s = __builtin_amdgcn_mfma_f32_32x32x16_bf16(kf, qf[kc], s, 0, 0, 0);
    }
    __builtin_amdgcn_s_setprio(0);
    // softmax m=0 (|scores| bounded; exact) -> in-register P fragments
#pragma unroll
    for (int r = 0; r < 16; ++r) { s[r] = __expf(s[r]); lsum += s[r]; }
    unsigned wA = cvtpk(s[0], s[1]),   wB = cvtpk(s[2], s[3]);
    unsigned wC = cvtpk(s[4], s[5]),   wD = cvtpk(s[6], s[7]);
    unsigned wE = cvtpk(s[8], s[9]),   wF = cvtpk(s[10], s[11]);
    unsigned wG = cvtpk(s[12], s[13]), wH = cvtpk(s[14], s[15]);
    bf16x8 pf0 = mkfrag(wA, wB, wC, wD, hb);
    bf16x8 pf1 = mkfrag(wE, wF, wG, wH, hb);
    // P·G: O^T[128 d'][32 q]
    __builtin_amdgcn_s_setprio(1);
#pragma unroll
    for (int dt = 0; dt < 4; ++dt) {
      o[dt] = __builtin_amdgcn_mfma_f32_32x32x16_bf16(vw[dt * 2],     pf0, o[dt], 0, 0, 0);
      o[dt] = __builtin_amdgcn_mfma_f32_32x32x16_bf16(vw[dt * 2 + 1], pf1, o[dt], 0, 0, 0);
    }
    __builtin_amdgcn_s_setprio(0);
    __syncthreads();       // drains next-tile staging; all waves done with kc_
  }

  lsum += __shfl_xor(lsum, 32);

  // ---- combine kv halves via LDS (K buffers dead) ----
  float* lsums = (float*)(sm.attn + 65536);
  if (w >= 4) {
    char* base = sm.attn + (w - 4) * 16384;
#pragma unroll
    for (int dt = 0; dt < 4; ++dt)
#pragma unroll
      for (int rq = 0; rq < 4; ++rq) {
        f32x4 v;
        v[0] = o[dt][rq * 4 + 0]; v[1] = o[dt][rq * 4 + 1];
        v[2] = o[dt][rq * 4 + 2]; v[3] = o[dt][rq * 4 + 3];
        *(f32x4*)(base + ((dt * 4 + rq) * 64 + l) * 16) = v;
      }
    if (l < 32) lsums[(w - 4) * 32 + l31] = lsum;
  }
  __syncthreads();
  if (w < 4) {
    const char* base = sm.attn + w * 16384;
#pragma unroll
    for (int dt = 0; dt < 4; ++dt)
#pragma unroll
      for (int rq = 0; rq < 4; ++rq) {
        f32x4 v = *(const f32x4*)(base + ((dt * 4 + rq) * 64 + l) * 16);
        o[dt][rq * 4 + 0] += v[0]; o[dt][rq * 4 + 1] += v[1];
        o[dt][rq * 4 + 2] += v[2]; o[dt][rq * 4 + 3] += v[3];
      }
    const float ltot = lsum + lsums[w * 32 + l31];
    const float linv = 1.f / ltot;
    float* orow = out + ((size_t)b * OUTR + qw + l31) * HID_;
#pragma unroll
    for (int dt = 0; dt < 4; ++dt) {
#pragma unroll
      for (int rq = 0; rq < 4; ++rq) {
        f32x4 bia = *(const f32x4*)(netb + dt * 32 + rq * 8 + h * 4);
        f32x4 vv;
        vv[0] = o[dt][4 * rq + 0] * linv + bia[0];
        vv[1] = o[dt][4 * rq + 1] * linv + bia[1];
        vv[2] = o[dt][4 * rq + 2] * linv + bia[2];
        vv[3] = o[dt][4 * rq + 3] * linv + bia[3];
        *(f32x4*)(orow + dt * 32 + rq * 8 + h * 4) = vv;
      }
    }
  }
}

extern "C" void kernel_launch(void* const* d_in, const int* in_sizes, int n_in,
                              void* d_out, int out_size, void* d_ws, size_t ws_size,
                              hipStream_t stream) {
  (void)in_sizes; (void)n_in; (void)out_size; (void)ws_size;
  const float* net_state  = (const float*)d_in[0];
  const float* sfc_state  = (const float*)d_in[1];
  const int*   node_pair  = (const int*)d_in[2];
  const float* Wq   = (const float*)d_in[3];
  const float* bq   = (const float*)d_in[4];
  const float* Wk   = (const float*)d_in[5];
  const float* bk   = (const float*)d_in[6];
  const float* Wv   = (const float*)d_in[7];
  const float* bv   = (const float*)d_in[8];
  const float* netW = (const float*)d_in[9];
  const float* netb = (const float*)d_in[10];
  const float* node_embed = (const float*)d_in[11];
  const float* sfcW = (const float*)d_in[12];
  const float* sfcb = (const float*)d_in[13];
  const float* pos  = (const float*)d_in[14];
  const float* qkvW = (const float*)d_in[15];
  const float* qkvB = (const float*)d_in[16];
  const float* outW = (const float*)d_in[17];
  const float* outB = (const float*)d_in[18];
  const float* ln1w = (const float*)d_in[19];
  const float* ln1b = (const float*)d_in[20];
  const float* l1w  = (const float*)d_in[21];
  const float* l1b  = (const float*)d_in[22];
  const float* l2w  = (const float*)d_in[23];
  const float* l2b  = (const float*)d_in[24];
  const float* ln2w = (const float*)d_in[25];
  const float* ln2b = (const float*)d_in[26];
  float* out = (float*)d_out;

  const size_t S = (size_t)B_ * N_ * DQ;       // 8,388,608 shorts
  short* Qb = (short*)d_ws;
  short* Kb = Qb + S;
  short* Gf = Kb + S;                          // 16 b x 64 nt x 8 frag x 512 = 4M shorts

  proj_kernel<<<256, 512, 0, stream>>>(net_state, Wq, bq, Wk, bk, Wv, bv, netW, Qb, Kb, Gf);
  attn_sfc_kernel<<<272, 512, 0, stream>>>(Qb, Kb, Gf, netb,
                                           sfc_state, node_pair, node_embed, sfcW, sfcb, pos,
                                           qkvW, qkvB, outW, outB, ln1w, ln1b, l1w, l1b,
                                           l2w, l2b, ln2w, ln2b, out);
}